// Round 11
// baseline (227.349 us; speedup 1.0000x reference)
//
#include <hip/hip_runtime.h>
#include <hip/hip_bf16.h>

#define H_DIM 1024
#define E_NUM 8
#define F_DIM 2048
#define N_TOK 2048   // B*S
typedef unsigned int uint;
typedef short bf16x8 __attribute__((ext_vector_type(8)));
typedef float f32x4 __attribute__((ext_vector_type(4)));

// ws layout (24.25 MB, same bound as all passing rounds)
#define WS_CNT   0
#define WS_OFF   64                        // int[9] exclusive prefix of cnt
#define WS_LIST  256                       // int[8*2048]
#define WS_W     (WS_LIST + 8*N_TOK*4)     // float[4096]
#define WS_G     131072                    // bf16 [4096][2048] = 16 MB (k-PERMUTED, SLOT-dense rows)
#define WS_AX    (WS_G + 4096*2048*2)      // bf16 [4096][1024] = 8 MB (k-PERMUTED, SLOT-dense)
#define WS_Y     WS_AX                     // y aliases Ax (Ax dead after G1)

// Row k-permutation: storage position of element k is
//   pi(k) = ((k>>5)*4 + ((k>>2)&3))*8 + ((k>>4)&1)*4 + (k&3)
// block-local to every 64-k step; each 16B chunk is one MFMA A-fragment k-set.

static __device__ __forceinline__ uint f2bf(float f) {
    uint u = __builtin_bit_cast(uint, f);
    return (u + 0x7FFFu + ((u >> 16) & 1u)) >> 16;   // RNE
}
static __device__ __forceinline__ float bflo(uint u) { return __builtin_bit_cast(float, u << 16); }
static __device__ __forceinline__ float bfhi(uint u) { return __builtin_bit_cast(float, u & 0xFFFF0000u); }
static __device__ __forceinline__ uint cvtpk(float a, float b) {
    uint r;
    asm("v_cvt_pk_bf16_f32 %0, %1, %2" : "=v"(r) : "v"(a), "v"(b));  // a->low16, b->high16
    return r;
}
static __device__ __forceinline__ void gload_lds16(const void* g, void* l) {
    __builtin_amdgcn_global_load_lds(
        (const __attribute__((address_space(1))) unsigned int*)g,
        (__attribute__((address_space(3))) unsigned int*)l,
        16, 0, 0);
}
template<int N> static __device__ __forceinline__ void vmwait() {
    if constexpr (N == 0)       asm volatile("s_waitcnt vmcnt(0)" ::: "memory");
    else if constexpr (N == 4)  asm volatile("s_waitcnt vmcnt(4)" ::: "memory");
    else if constexpr (N == 12) asm volatile("s_waitcnt vmcnt(12)" ::: "memory");
    else if constexpr (N == 16) asm volatile("s_waitcnt vmcnt(16)" ::: "memory");
}
static __device__ __forceinline__ void lgk0_bar() {
    asm volatile("s_waitcnt lgkmcnt(0)" ::: "memory");
    __builtin_amdgcn_s_barrier();
    asm volatile("" ::: "memory");
}

// ---------------- router ----------------
__global__ __launch_bounds__(256) void router_kernel(
    const float* __restrict__ x, const float* __restrict__ rw,
    int* __restrict__ cnt, int* __restrict__ list, float* __restrict__ w_entry)
{
    int wave = threadIdx.x >> 6, lane = threadIdx.x & 63;
    int n = blockIdx.x * 4 + wave;
    const float* xr = x + (size_t)n * H_DIM;
    float acc[8] = {0,0,0,0,0,0,0,0};
    #pragma unroll
    for (int i = 0; i < H_DIM/64; ++i) {
        int h = i*64 + lane;
        float xv = xr[h];
        const float4* rr = (const float4*)(rw + (size_t)h*8);
        float4 r0 = rr[0], r1 = rr[1];
        acc[0] += xv*r0.x; acc[1] += xv*r0.y; acc[2] += xv*r0.z; acc[3] += xv*r0.w;
        acc[4] += xv*r1.x; acc[5] += xv*r1.y; acc[6] += xv*r1.z; acc[7] += xv*r1.w;
    }
    #pragma unroll
    for (int e = 0; e < 8; ++e) {
        float v = acc[e];
        #pragma unroll
        for (int off = 32; off; off >>= 1) v += __shfl_xor(v, off);
        acc[e] = v;
    }
    int e0 = 0;
    #pragma unroll
    for (int e = 1; e < 8; ++e) if (acc[e] > acc[e0]) e0 = e;
    int e1 = -1;
    #pragma unroll
    for (int e = 0; e < 8; ++e) if (e != e0 && (e1 < 0 || acc[e] > acc[e1])) e1 = e;
    float w0 = 1.0f / (1.0f + __expf(acc[e1] - acc[e0]));
    float w1 = 1.0f - w0;
    if (lane == 0) {
        int p0 = atomicAdd(&cnt[e0], 1);
        list[e0*N_TOK + p0] = n*2;
        w_entry[n*2] = w0;
        int p1 = atomicAdd(&cnt[e1], 1);
        list[e1*N_TOK + p1] = n*2 + 1;
        w_entry[n*2+1] = w1;
    }
}

// ---------------- prefix ----------------
__global__ void prefix_kernel(const int* __restrict__ cnt, int* __restrict__ off) {
    if (threadIdx.x == 0) {
        int s = 0;
        #pragma unroll
        for (int e = 0; e < E_NUM; ++e) { off[e] = s; s += cnt[e]; }
        off[E_NUM] = s;
    }
}

// ---------------- gather: x[token] -> Ax[slot] bf16 k-permuted (coalesced) ----------------
__global__ __launch_bounds__(256) void gather_kernel(
    const float* __restrict__ x, const int* __restrict__ cnt, const int* __restrict__ off,
    const int* __restrict__ list, unsigned short* __restrict__ Ax)
{
    int e = blockIdx.x >> 9;                 // 512 blocks/expert, 4 rows/block
    int r = (blockIdx.x & 511)*4 + (threadIdx.x >> 6);
    int lane = threadIdx.x & 63;
    if (r >= cnt[e]) return;
    int ent = list[e*N_TOK + r];
    const float* xr = x + (size_t)(ent >> 1) * H_DIM;
    unsigned short* dr = Ax + (size_t)(off[e] + r) * H_DIM;
    #pragma unroll
    for (int q = 0; q < 2; ++q) {
        int b = lane*2 + q;
        int t = b >> 3, s = b & 7;
        int klo = t*64 + (s >> 2)*32 + (s & 3)*4;
        float4 lo = *(const float4*)(xr + klo);
        float4 hi = *(const float4*)(xr + klo + 16);
        uint4 o;
        o.x = cvtpk(lo.x, lo.y); o.y = cvtpk(lo.z, lo.w);
        o.z = cvtpk(hi.x, hi.y); o.w = cvtpk(hi.z, hi.w);
        *(uint4*)(dr + b*8) = o;
    }
}

// ---------------- fused expert GEMM (R10 schedule, contiguous slot-dense A) ----------------
// 128x128 tile, 4 waves col-split. A: bf16 k-permuted glds from CONTIGUOUS slot rows,
// 4-deep. B: fp32 global -> regs (2 pairs ahead, counted) -> cvtpk -> ds_write into
// kpair-packed bf16 Bs[2]. Steady queue 24 in flight; vmcnt(16); never 0 in loop.
template<int IS_G1>
__global__ __launch_bounds__(256, 2) void moe_gemm_kernel(
    const unsigned short* __restrict__ Asrc, const float* __restrict__ W,
    const int* __restrict__ cnt, const int* __restrict__ off,
    const int* __restrict__ list, const float* __restrict__ w_entry,
    unsigned short* __restrict__ dst)
{
    constexpr int KTOT  = IS_G1 ? H_DIM : F_DIM;
    constexpr int BLD   = IS_G1 ? 2*F_DIM : H_DIM;   // W row stride (fp32)
    constexpr int DLD   = IS_G1 ? F_DIM : H_DIM;     // dst row stride
    constexpr int ALD   = IS_G1 ? H_DIM : F_DIM;     // A src row stride (shorts)
    constexpr int ROWS  = 128;
    constexpr int NM    = 8;
    constexpr int NA    = 4;                         // A glds per wave per 64k tile
    constexpr int NMT   = 16;
    constexpr int NNT   = IS_G1 ? 32 : 8;
    constexpr int NP    = KTOT / 64;                 // 64k pairs (16 / 32)

    __shared__ __align__(16) unsigned short As[4][ROWS*64];  // 4 x 16 KB
    __shared__ __align__(16) uint Bs[2][16*128];             // 2 x 8 KB bf16 kpair-packed

    constexpr int nb = NMT * NNT * E_NUM;
    constexpr int chunk = nb >> 3;
    int bid = blockIdx.x;
    int f  = (bid & 7) * chunk + (bid >> 3);
    int mt = f % NMT;
    int nt = (f / NMT) % NNT;
    int e  = f / (NMT * NNT);

    const int c = cnt[e];
    if (mt * ROWS >= c) return;
    const int abase = off[e] + mt * ROWS;            // dense slot base
    const int tid = threadIdx.x;
    const int lane = tid & 63, wid = tid >> 6;
    const int l15 = lane & 15, lg = lane >> 4;

    // A staging sources: CONTIGUOUS slot rows (8 lanes = one 128B line each)
    const unsigned short* a_src[NA];
    #pragma unroll
    for (int i = 0; i < NA; ++i) {
        int sl  = wid*(NA*1024) + i*1024 + lane*16;
        int row = sl >> 7;
        int kb  = ((sl >> 4) & 7) ^ (row & 7);
        int gr  = abase + row; gr = gr < 4095 ? gr : 4095;   // stay inside Ax/g
        a_src[i] = Asrc + (size_t)gr * ALD + kb*8;
    }

    // B staging (verified formulas): per 32k tile, thread covers 2 chunks
    const float* Wb = W + (size_t)e * (size_t)(IS_G1 ? H_DIM*2*F_DIM : F_DIM*H_DIM);
    const float* b_src[2]; int b_dst[2];
    #pragma unroll
    for (int s = 0; s < 2; ++s) {
        int q = tid + s*256;
        int kp = q >> 5, c4 = q & 31;                // kp 0..15
        int gc;
        if constexpr (IS_G1) gc = (c4 < 16) ? (nt*64 + 4*c4) : (F_DIM + nt*64 + 4*(c4-16));
        else                 gc = nt*128 + 4*c4;
        b_src[s] = Wb + (size_t)(2*kp) * BLD + gc;
        b_dst[s] = (kp*512 + c4*16) ^ ((kp & 4) << 4);
    }

    // fragment addresses (verified)
    int a_addr[NM][2];
    #pragma unroll
    for (int m = 0; m < NM; ++m)
        #pragma unroll
        for (int p = 0; p < 2; ++p) {
            int row = m*16 + l15;
            a_addr[m][p] = row*128 + ((p*64 + lg*16) ^ ((row & 7) << 4));
        }
    int b_base[2];
    const int xorv = ((2*lg) & 4) << 4;
    #pragma unroll
    for (int j = 0; j < 2; ++j) {
        int cb = IS_G1 ? (j ? (4 + wid) : wid) : (wid*2 + j);
        b_base[j] = (2*lg)*512 + (((cb*16 + l15) * 4) ^ xorv);
    }

    f32x4 acc[NM][2];
    #pragma unroll
    for (int m = 0; m < NM; ++m)
        #pragma unroll
        for (int j = 0; j < 2; ++j) acc[m][j] = (f32x4){0.f,0.f,0.f,0.f};

    struct BQ { float4 a0, a1, b0, b1; };
    auto loadB = [&](int t) {
        BQ q;
        const float* p0 = b_src[0] + (size_t)t * 32 * BLD;
        q.a0 = *(const float4*)p0;
        q.a1 = *(const float4*)(p0 + BLD);
        const float* p1 = b_src[1] + (size_t)t * 32 * BLD;
        q.b0 = *(const float4*)p1;
        q.b1 = *(const float4*)(p1 + BLD);
        return q;
    };
    auto dswB = [&](const BQ& q, int buf) {
        uint4 w0, w1;
        w0.x = cvtpk(q.a0.x, q.a1.x); w0.y = cvtpk(q.a0.y, q.a1.y);
        w0.z = cvtpk(q.a0.z, q.a1.z); w0.w = cvtpk(q.a0.w, q.a1.w);
        w1.x = cvtpk(q.b0.x, q.b1.x); w1.y = cvtpk(q.b0.y, q.b1.y);
        w1.z = cvtpk(q.b0.z, q.b1.z); w1.w = cvtpk(q.b0.w, q.b1.w);
        *(uint4*)((char*)Bs[buf] + b_dst[0]) = w0;
        *(uint4*)((char*)Bs[buf] + b_dst[1]) = w1;
    };
    auto STAGE_A = [&](int s) {
        #pragma unroll
        for (int i = 0; i < NA; ++i)
            gload_lds16(a_src[i] + s*64, (char*)As[s & 3] + wid*(NA*1024) + i*1024);
    };
    auto compute = [&](int P, int abuf) {            // P literal at call sites
        const char* ab  = (const char*)As + abuf*(ROWS*128);
        const char* bb0 = (const char*)Bs[P];
        bf16x8 bfr[2];
        #pragma unroll
        for (int j = 0; j < 2; ++j) {
            const char* bb = bb0 + b_base[j];
            union { uint u[4]; bf16x8 v; } bu;
            bu.u[0] = *(const uint*)(bb);
            bu.u[1] = *(const uint*)(bb + 512);
            bu.u[2] = *(const uint*)(bb + 8*512);
            bu.u[3] = *(const uint*)(bb + 9*512);
            bfr[j] = bu.v;
        }
        #pragma unroll
        for (int m = 0; m < NM; ++m) {
            bf16x8 af = *(const bf16x8*)(ab + (P ? a_addr[m][1] : a_addr[m][0]));
            #pragma unroll
            for (int j = 0; j < 2; ++j)
                acc[m][j] = __builtin_amdgcn_mfma_f32_16x16x32_bf16(af, bfr[j], acc[m][j], 0, 0, 0);
        }
    };

    // ---- prologue: queue order [A0, B0, B1, A1, B2, B3] = 24 in flight ----
    STAGE_A(0);
    BQ q0 = loadB(0);
    BQ q1 = loadB(1);
    STAGE_A(1);
    BQ q2 = loadB(2);
    BQ q3 = loadB(3);

    // ---- steady loop: 2 pairs per iteration, vmcnt(16) throughout ----
    for (int tp = 0; tp < NP - 2; tp += 2) {
        const int t = 2*tp;
        vmwait<16>(); __builtin_amdgcn_sched_barrier(0);
        dswB(q0, 0);
        lgk0_bar();
        STAGE_A(tp + 2);
        compute(0, tp & 3);
        vmwait<16>(); __builtin_amdgcn_sched_barrier(0);
        dswB(q1, 1);
        lgk0_bar();
        q0 = loadB(t + 4);
        q1 = loadB(t + 5);
        compute(1, tp & 3);
        vmwait<16>(); __builtin_amdgcn_sched_barrier(0);
        dswB(q2, 0);
        lgk0_bar();
        STAGE_A(tp + 3);
        compute(0, (tp + 1) & 3);
        vmwait<16>(); __builtin_amdgcn_sched_barrier(0);
        dswB(q3, 1);
        lgk0_bar();
        q2 = loadB(t + 6);
        q3 = loadB(t + 7);
        compute(1, (tp + 1) & 3);
    }
    // ---- tail ----
    {
        vmwait<16>(); __builtin_amdgcn_sched_barrier(0);
        dswB(q0, 0);
        lgk0_bar();
        compute(0, (NP - 2) & 3);
        vmwait<12>(); __builtin_amdgcn_sched_barrier(0);
        dswB(q1, 1);
        lgk0_bar();
        compute(1, (NP - 2) & 3);
        vmwait<4>(); __builtin_amdgcn_sched_barrier(0);
        dswB(q2, 0);
        lgk0_bar();
        compute(0, (NP - 1) & 3);
        vmwait<0>(); __builtin_amdgcn_sched_barrier(0);
        dswB(q3, 1);
        lgk0_bar();
        compute(1, (NP - 1) & 3);
    }

    // ---- epilogue (coalesced via LDS transpose in As) ----
    if constexpr (IS_G1) {
        __syncthreads();
        unsigned short (*tb)[64] = (unsigned short (*)[64])As;  // 128x64 bf16 = 16 KB
        const int pcol = ((wid >> 1)*4 + (l15 >> 2))*8 + (wid & 1)*4 + (l15 & 3);
        #pragma unroll
        for (int m = 0; m < NM; ++m) {
            f32x4 ga = acc[m][0], gv = acc[m][1];
            #pragma unroll
            for (int i = 0; i < 4; ++i) {
                int row = m*16 + lg*4 + i;
                float a = ga[i];
                tb[row][pcol] = (unsigned short)f2bf((a / (1.f + __expf(-a))) * gv[i]);
            }
        }
        __syncthreads();
        int r = tid >> 1, half = tid & 1;
        if (mt*ROWS + r < c) {
            // write g at the DENSE SLOT row (no list lookup)
            char* dp = (char*)dst + ((size_t)(abase + r) * DLD + nt*64)*2 + half*64;
            const char* sp = (const char*)&tb[r][0] + half*64;
            #pragma unroll
            for (int qq = 0; qq < 4; ++qq)
                *(uint4*)(dp + qq*16) = *(const uint4*)(sp + qq*16);
        }
    } else {
        const int lbase = e * N_TOK + mt * ROWS;
        float (*tb)[128] = (float (*)[128])As;   // 32x128 f32 = 16 KB
        #pragma unroll
        for (int h = 0; h < 4; ++h) {
            __syncthreads();
            #pragma unroll
            for (int mm = 0; mm < 2; ++mm) {
                int m = h*2 + mm;
                #pragma unroll
                for (int j = 0; j < 2; ++j)
                    #pragma unroll
                    for (int i = 0; i < 4; ++i) {
                        int row = mm*16 + lg*4 + i;
                        tb[row][(wid*2 + j)*16 + l15] = acc[m][j][i];
                    }
            }
            __syncthreads();
            int r = tid >> 3, ch = tid & 7;
            int rg = h*32 + r;
            if (mt*ROWS + rg < c) {
                int ent = list[lbase + rg];
                float w = w_entry[ent];
                const float* src = &tb[r][ch*16];
                uint4 o0, o1;
                o0.x = cvtpk(w*src[0],  w*src[1]);  o0.y = cvtpk(w*src[2],  w*src[3]);
                o0.z = cvtpk(w*src[4],  w*src[5]);  o0.w = cvtpk(w*src[6],  w*src[7]);
                o1.x = cvtpk(w*src[8],  w*src[9]);  o1.y = cvtpk(w*src[10], w*src[11]);
                o1.z = cvtpk(w*src[12], w*src[13]); o1.w = cvtpk(w*src[14], w*src[15]);
                char* dp = (char*)dst + ((size_t)ent * DLD + nt*128 + ch*16)*2;
                *(uint4*)(dp)      = o0;
                *(uint4*)(dp + 16) = o1;
            }
        }
    }
}

// ---------------- combine ----------------
__global__ __launch_bounds__(256) void combine_kernel(
    const unsigned short* __restrict__ y, float* __restrict__ out)
{
    int gid = blockIdx.x * 256 + threadIdx.x;
    size_t base = (size_t)gid * 8;
    int n = (int)(base >> 10), h = (int)(base & 1023);
    const uint4 a = *(const uint4*)(y + (size_t)(2*n)   * 1024 + h);
    const uint4 b = *(const uint4*)(y + (size_t)(2*n+1) * 1024 + h);
    float4 o0, o1;
    o0.x = bflo(a.x)+bflo(b.x); o0.y = bfhi(a.x)+bfhi(b.x);
    o0.z = bflo(a.y)+bflo(b.y); o0.w = bfhi(a.y)+bfhi(b.y);
    o1.x = bflo(a.z)+bflo(b.z); o1.y = bfhi(a.z)+bfhi(b.z);
    o1.z = bflo(a.w)+bflo(b.w); o1.w = bfhi(a.w)+bfhi(b.w);
    *(float4*)(out + base)     = o0;
    *(float4*)(out + base + 4) = o1;
}

extern "C" void kernel_launch(void* const* d_in, const int* in_sizes, int n_in,
                              void* d_out, int out_size, void* d_ws, size_t ws_size,
                              hipStream_t stream) {
    const float* x  = (const float*)d_in[0];
    const float* rw = (const float*)d_in[1];
    const float* W1 = (const float*)d_in[2];
    const float* W2 = (const float*)d_in[3];
    float* out = (float*)d_out;
    char* ws = (char*)d_ws;
    int*   cnt     = (int*)(ws + WS_CNT);
    int*   off     = (int*)(ws + WS_OFF);
    int*   list    = (int*)(ws + WS_LIST);
    float* w_entry = (float*)(ws + WS_W);
    unsigned short* g  = (unsigned short*)(ws + WS_G);
    unsigned short* Ax = (unsigned short*)(ws + WS_AX);
    unsigned short* y  = (unsigned short*)(ws + WS_Y);   // aliases Ax (dead after G1)

    hipMemsetAsync(cnt, 0, E_NUM * sizeof(int), stream);
    router_kernel<<<N_TOK/4, 256, 0, stream>>>(x, rw, cnt, list, w_entry);
    prefix_kernel<<<1, 64, 0, stream>>>(cnt, off);
    gather_kernel<<<E_NUM*512, 256, 0, stream>>>(x, cnt, off, list, Ax);
    moe_gemm_kernel<1><<<16*32*E_NUM, 256, 0, stream>>>(Ax, W1, cnt, off, list, w_entry, g);
    moe_gemm_kernel<0><<<16*8*E_NUM, 256, 0, stream>>>(g,  W2, cnt, off, list, w_entry, y);
    combine_kernel<<<(out_size/8 + 255)/256, 256, 0, stream>>>(y, out);
}

// Round 13
// 203.505 us; speedup vs baseline: 1.1172x; 1.1172x over previous
//
#include <hip/hip_runtime.h>
#include <hip/hip_bf16.h>

#define H_DIM 1024
#define E_NUM 8
#define F_DIM 2048
#define N_TOK 2048   // B*S
typedef unsigned int uint;
typedef short bf16x8 __attribute__((ext_vector_type(8)));
typedef float f32x4 __attribute__((ext_vector_type(4)));

// ws layout (24.25 MB)
#define WS_CNT   0
#define WS_OFF   64                        // int[9] exclusive prefix of cnt
#define WS_LIST  256                       // int[8*2048]
#define WS_W     (WS_LIST + 8*N_TOK*4)     // float[4096]
#define WS_G     131072                    // bf16 [4096][2048] (k-PERMUTED, SLOT-dense)
#define WS_AX    (WS_G + 4096*2048*2)      // bf16 [4096][1024] (k-PERMUTED, SLOT-dense)
#define WS_Y     WS_AX                     // y aliases Ax (Ax dead after G1)

// Row k-permutation: storage position of element k is
//   pi(k) = ((k>>5)*4 + ((k>>2)&3))*8 + ((k>>4)&1)*4 + (k&3)  (per 64-k block)

static __device__ __forceinline__ uint f2bf(float f) {
    uint u = __builtin_bit_cast(uint, f);
    return (u + 0x7FFFu + ((u >> 16) & 1u)) >> 16;   // RNE
}
static __device__ __forceinline__ float bflo(uint u) { return __builtin_bit_cast(float, u << 16); }
static __device__ __forceinline__ float bfhi(uint u) { return __builtin_bit_cast(float, u & 0xFFFF0000u); }
static __device__ __forceinline__ uint cvtpk(float a, float b) {
    uint r;
    asm("v_cvt_pk_bf16_f32 %0, %1, %2" : "=v"(r) : "v"(a), "v"(b));
    return r;
}
static __device__ __forceinline__ void gload_lds16(const void* g, void* l) {
    __builtin_amdgcn_global_load_lds(
        (const __attribute__((address_space(1))) unsigned int*)g,
        (__attribute__((address_space(3))) unsigned int*)l,
        16, 0, 0);
}
template<int N> static __device__ __forceinline__ void vmwait() {
    if constexpr (N == 0)      asm volatile("s_waitcnt vmcnt(0)" ::: "memory");
    else if constexpr (N == 2) asm volatile("s_waitcnt vmcnt(2)" ::: "memory");
    else if constexpr (N == 4) asm volatile("s_waitcnt vmcnt(4)" ::: "memory");
}
// lgkmcnt(0) + sched fence + barrier + fence: makes own ds_writes visible and
// separates all preceding LDS reads from subsequent writes (double-buffer handoff).
static __device__ __forceinline__ void lgk0_bar() {
    asm volatile("s_waitcnt lgkmcnt(0)" ::: "memory");
    __builtin_amdgcn_sched_barrier(0);
    __builtin_amdgcn_s_barrier();
    asm volatile("" ::: "memory");
}

// ---------------- router ----------------
__global__ __launch_bounds__(256) void router_kernel(
    const float* __restrict__ x, const float* __restrict__ rw,
    int* __restrict__ cnt, int* __restrict__ list, float* __restrict__ w_entry)
{
    int wave = threadIdx.x >> 6, lane = threadIdx.x & 63;
    int n = blockIdx.x * 4 + wave;
    const float* xr = x + (size_t)n * H_DIM;
    float acc[8] = {0,0,0,0,0,0,0,0};
    #pragma unroll
    for (int i = 0; i < H_DIM/64; ++i) {
        int h = i*64 + lane;
        float xv = xr[h];
        const float4* rr = (const float4*)(rw + (size_t)h*8);
        float4 r0 = rr[0], r1 = rr[1];
        acc[0] += xv*r0.x; acc[1] += xv*r0.y; acc[2] += xv*r0.z; acc[3] += xv*r0.w;
        acc[4] += xv*r1.x; acc[5] += xv*r1.y; acc[6] += xv*r1.z; acc[7] += xv*r1.w;
    }
    #pragma unroll
    for (int e = 0; e < 8; ++e) {
        float v = acc[e];
        #pragma unroll
        for (int off = 32; off; off >>= 1) v += __shfl_xor(v, off);
        acc[e] = v;
    }
    int e0 = 0;
    #pragma unroll
    for (int e = 1; e < 8; ++e) if (acc[e] > acc[e0]) e0 = e;
    int e1 = -1;
    #pragma unroll
    for (int e = 0; e < 8; ++e) if (e != e0 && (e1 < 0 || acc[e] > acc[e1])) e1 = e;
    float w0 = 1.0f / (1.0f + __expf(acc[e1] - acc[e0]));
    float w1 = 1.0f - w0;
    if (lane == 0) {
        int p0 = atomicAdd(&cnt[e0], 1);
        list[e0*N_TOK + p0] = n*2;
        w_entry[n*2] = w0;
        int p1 = atomicAdd(&cnt[e1], 1);
        list[e1*N_TOK + p1] = n*2 + 1;
        w_entry[n*2+1] = w1;
    }
}

// ---------------- prefix ----------------
__global__ void prefix_kernel(const int* __restrict__ cnt, int* __restrict__ off) {
    if (threadIdx.x == 0) {
        int s = 0;
        #pragma unroll
        for (int e = 0; e < E_NUM; ++e) { off[e] = s; s += cnt[e]; }
        off[E_NUM] = s;
    }
}

// ---------------- gather: x[token] -> Ax[slot] bf16 k-permuted ----------------
__global__ __launch_bounds__(256) void gather_kernel(
    const float* __restrict__ x, const int* __restrict__ cnt, const int* __restrict__ off,
    const int* __restrict__ list, unsigned short* __restrict__ Ax)
{
    int e = blockIdx.x >> 9;
    int r = (blockIdx.x & 511)*4 + (threadIdx.x >> 6);
    int lane = threadIdx.x & 63;
    if (r >= cnt[e]) return;
    int ent = list[e*N_TOK + r];
    const float* xr = x + (size_t)(ent >> 1) * H_DIM;
    unsigned short* dr = Ax + (size_t)(off[e] + r) * H_DIM;
    #pragma unroll
    for (int q = 0; q < 2; ++q) {
        int b = lane*2 + q;
        int t = b >> 3, s = b & 7;
        int klo = t*64 + (s >> 2)*32 + (s & 3)*4;
        float4 lo = *(const float4*)(xr + klo);
        float4 hi = *(const float4*)(xr + klo + 16);
        uint4 o;
        o.x = cvtpk(lo.x, lo.y); o.y = cvtpk(lo.z, lo.w);
        o.z = cvtpk(hi.x, hi.y); o.w = cvtpk(hi.z, hi.w);
        *(uint4*)(dr + b*8) = o;
    }
}

// ---------------- fused expert GEMM ----------------
// R6 geometry + counted-vmcnt schedule, DOUBLE-BUFFERED Bs (race-free handoff:
// every Bs write is separated from that buffer's readers by a lgk0_bar).
// compute(0) reads Bs[0] (even 32k step), compute(1) reads Bs[1] (odd step).
template<int IS_G1>
__global__ __launch_bounds__(256, IS_G1 ? 4 : 5) void moe_gemm_kernel(
    const unsigned short* __restrict__ Asrc, const float* __restrict__ W,
    const int* __restrict__ cnt, const int* __restrict__ off,
    const int* __restrict__ list, const float* __restrict__ w_entry,
    unsigned short* __restrict__ dst)
{
    constexpr int KTOT  = IS_G1 ? H_DIM : F_DIM;
    constexpr int BLD   = IS_G1 ? 2*F_DIM : H_DIM;   // W row stride (fp32)
    constexpr int DLD   = IS_G1 ? F_DIM : H_DIM;     // dst row stride
    constexpr int ALD   = IS_G1 ? H_DIM : F_DIM;     // A src row stride (shorts)
    constexpr int ROWS  = 64;
    constexpr int NM    = IS_G1 ? 4 : 2;
    constexpr int NMT   = 32;
    constexpr int NNT   = IS_G1 ? 32 : 16;
    constexpr int BSROW = IS_G1 ? 512 : 256;         // Bs kpair row bytes
    constexpr int NBS   = IS_G1 ? 2 : 1;             // uint4 Bs slots per thread
    constexpr int NT2   = KTOT / 64;                 // 64k pairs

    __shared__ __align__(16) unsigned short As[2][ROWS*64];  // 2 x 8 KB
    __shared__ __align__(16) uint Bs[2][16*BSROW/4];         // 2 x 8/4 KB bf16 kpair

    constexpr int nb = NMT * NNT * E_NUM;
    constexpr int chunk = nb >> 3;
    int bid = blockIdx.x;
    int f  = (bid & 7) * chunk + (bid >> 3);
    int mt = f % NMT;
    int nt = (f / NMT) % NNT;
    int e  = f / (NMT * NNT);

    const int c = cnt[e];
    if (mt * ROWS >= c) return;
    const int abase = off[e] + mt * ROWS;
    const int tid = threadIdx.x;
    const int lane = tid & 63, wid = tid >> 6;
    const int l15 = lane & 15, lg = lane >> 4;
    const int wr = IS_G1 ? 0 : (wid >> 1);
    const int wc = wid & 1;
    const int rowbase = IS_G1 ? 0 : wr*32;

    // A staging sources (pre-swizzled: linear glds dest == bank-swizzled layout)
    const unsigned short* a_src[2];
    #pragma unroll
    for (int i = 0; i < 2; ++i) {
        int sl  = wid*2048 + i*1024 + lane*16;
        int row = sl >> 7;
        int kb  = ((sl >> 4) & 7) ^ (row & 7);
        int gr  = abase + row; gr = gr < 4095 ? gr : 4095;
        a_src[i] = Asrc + (size_t)gr * ALD + kb*8;
    }

    // B staging (verified BK=32 forms)
    const float* Wb = W + (size_t)e * (size_t)(IS_G1 ? H_DIM*2*F_DIM : F_DIM*H_DIM);
    const float* b_src[NBS]; int b_dst[NBS];
    #pragma unroll
    for (int s = 0; s < NBS; ++s) {
        int q = tid + s*256;
        int kp, c4, gc;
        if constexpr (IS_G1) {
            kp = q >> 5; c4 = q & 31;
            gc = (c4 < 16) ? (nt*64 + 4*c4) : (F_DIM + nt*64 + 4*(c4-16));
        } else {
            kp = q >> 4; c4 = q & 15;
            gc = nt*64 + 4*c4;
        }
        b_src[s] = Wb + (size_t)(2*kp) * BLD + gc;
        b_dst[s] = (kp*BSROW + c4*16) ^ ((kp & 4) << 4);
    }

    // fragment addresses (verified)
    int a_addr[NM][2];
    #pragma unroll
    for (int m = 0; m < NM; ++m)
        #pragma unroll
        for (int p = 0; p < 2; ++p) {
            int row = rowbase + m*16 + l15;
            a_addr[m][p] = row*128 + ((p*64 + lg*16) ^ ((row & 7) << 4));
        }
    int b_base[2];
    const int xorv = ((2*lg) & 4) << 4;
    #pragma unroll
    for (int j = 0; j < 2; ++j) {
        int cb = IS_G1 ? (j ? (4 + wid) : wid) : (wc*2 + j);
        b_base[j] = (2*lg)*BSROW + (((cb*16 + l15) * 4) ^ xorv);
    }

    f32x4 acc[NM][2];
    #pragma unroll
    for (int m = 0; m < NM; ++m)
        #pragma unroll
        for (int j = 0; j < 2; ++j) acc[m][j] = (f32x4){0.f,0.f,0.f,0.f};

    struct BQ { float4 r0[NBS], r1[NBS]; };
    auto loadB = [&](int t) {
        BQ q;
        #pragma unroll
        for (int s = 0; s < NBS; ++s) {
            const float* p = b_src[s] + (size_t)t * 32 * BLD;
            q.r0[s] = *(const float4*)p;
            q.r1[s] = *(const float4*)(p + BLD);
        }
        return q;
    };
    auto dswB = [&](const BQ& q, int buf) {
        #pragma unroll
        for (int s = 0; s < NBS; ++s) {
            uint4 w4;
            w4.x = cvtpk(q.r0[s].x, q.r1[s].x); w4.y = cvtpk(q.r0[s].y, q.r1[s].y);
            w4.z = cvtpk(q.r0[s].z, q.r1[s].z); w4.w = cvtpk(q.r0[s].w, q.r1[s].w);
            *(uint4*)((char*)Bs[buf] + b_dst[s]) = w4;
        }
    };
    auto STAGE_A = [&](int a) {
        #pragma unroll
        for (int i = 0; i < 2; ++i)
            gload_lds16(a_src[i] + a*64, (char*)As[a & 1] + wid*2048 + i*1024);
    };
    auto compute = [&](int P, int abuf) {            // P literal at call sites; B buffer == P
        const char* ab  = (const char*)As[abuf];
        const char* bb0 = (const char*)Bs[P];
        bf16x8 bfr[2];
        #pragma unroll
        for (int j = 0; j < 2; ++j) {
            const char* bb = bb0 + b_base[j];
            union { uint u[4]; bf16x8 v; } bu;
            bu.u[0] = *(const uint*)(bb);
            bu.u[1] = *(const uint*)(bb + BSROW);
            bu.u[2] = *(const uint*)(bb + 8*BSROW);
            bu.u[3] = *(const uint*)(bb + 9*BSROW);
            bfr[j] = bu.v;
        }
        #pragma unroll
        for (int m = 0; m < NM; ++m) {
            bf16x8 af = *(const bf16x8*)(ab + (P ? a_addr[m][1] : a_addr[m][0]));
            #pragma unroll
            for (int j = 0; j < 2; ++j)
                acc[m][j] = __builtin_amdgcn_mfma_f32_16x16x32_bf16(af, bfr[j], acc[m][j], 0, 0, 0);
        }
    };

    // ---- prologue ----
    STAGE_A(0);
    { BQ q0 = loadB(0); dswB(q0, 0); }   // compiler drains (one-time); Bs[0] = B(0)
    BQ qW = loadB(1);
    BQ qN;

    // ---- main loop: one lgk0_bar per 32k step; writes always target the buffer
    //      whose readers finished before the previous barrier ----
    for (int tp = 0; tp < NT2 - 1; ++tp) {
        vmwait<2*NBS>(); __builtin_amdgcn_sched_barrier(0);
        lgk0_bar();                      // Bs[0]=B(2tp) visible; A(tp) ready (drained prev pair)
        STAGE_A(tp + 1);
        qN = loadB(2*tp + 2);
        compute(0, tp & 1);              // reads Bs[0]
        dswB(qW, 1);                     // write B(2tp+1) -> Bs[1] (readers done: prev entry bar)
        lgk0_bar();                      // Bs[1] visible; Bs[0] readers done
        qW = loadB(2*tp + 3);
        compute(1, tp & 1);              // reads Bs[1]
        dswB(qN, 0);                     // write B(2tp+2) -> Bs[0] (readers done: mid bar)
    }
    // ---- tail pair tp = NT2-1 ----
    {
        const int ab = (NT2 - 1) & 1;
        vmwait<2*NBS>(); __builtin_amdgcn_sched_barrier(0);
        lgk0_bar();
        compute(0, ab);
        dswB(qW, 1);                     // compiler waits qW loads
        lgk0_bar();
        compute(1, ab);
    }

    // ---- epilogue (verbatim R12) ----
    if constexpr (IS_G1) {
        const int pbase = nt*64 + ((wid >> 1)*4 + (l15 >> 2))*8 + (wid & 1)*4 + (l15 & 3);
        #pragma unroll
        for (int m = 0; m < NM; ++m) {
            f32x4 ga = acc[m][0], gv = acc[m][1];
            #pragma unroll
            for (int i = 0; i < 4; ++i) {
                int rl = m*16 + lg*4 + i;
                if (mt*ROWS + rl < c) {
                    float a = ga[i];
                    float g = (a / (1.f + __expf(-a))) * gv[i];
                    dst[(size_t)(abase + rl) * DLD + pbase] = (unsigned short)f2bf(g);
                }
            }
        }
    } else {
        const int lbase = e * N_TOK + mt * ROWS;
        #pragma unroll
        for (int m = 0; m < NM; ++m)
            #pragma unroll
            for (int i = 0; i < 4; ++i) {
                int rl = rowbase + m*16 + lg*4 + i;
                if (mt*ROWS + rl < c) {
                    int ent = list[lbase + rl];
                    float w = w_entry[ent];
                    #pragma unroll
                    for (int j = 0; j < 2; ++j) {
                        int col = nt*64 + wc*32 + j*16 + l15;
                        dst[(size_t)ent * DLD + col] = (unsigned short)f2bf(w * acc[m][j][i]);
                    }
                }
            }
    }
}

// ---------------- combine ----------------
__global__ __launch_bounds__(256) void combine_kernel(
    const unsigned short* __restrict__ y, float* __restrict__ out)
{
    int gid = blockIdx.x * 256 + threadIdx.x;
    size_t base = (size_t)gid * 8;
    int n = (int)(base >> 10), h = (int)(base & 1023);
    const uint4 a = *(const uint4*)(y + (size_t)(2*n)   * 1024 + h);
    const uint4 b = *(const uint4*)(y + (size_t)(2*n+1) * 1024 + h);
    float4 o0, o1;
    o0.x = bflo(a.x)+bflo(b.x); o0.y = bfhi(a.x)+bfhi(b.x);
    o0.z = bflo(a.y)+bflo(b.y); o0.w = bfhi(a.y)+bfhi(b.y);
    o1.x = bflo(a.z)+bflo(b.z); o1.y = bfhi(a.z)+bfhi(b.z);
    o1.z = bflo(a.w)+bflo(b.w); o1.w = bfhi(a.w)+bfhi(b.w);
    *(float4*)(out + base)     = o0;
    *(float4*)(out + base + 4) = o1;
}

extern "C" void kernel_launch(void* const* d_in, const int* in_sizes, int n_in,
                              void* d_out, int out_size, void* d_ws, size_t ws_size,
                              hipStream_t stream) {
    const float* x  = (const float*)d_in[0];
    const float* rw = (const float*)d_in[1];
    const float* W1 = (const float*)d_in[2];
    const float* W2 = (const float*)d_in[3];
    float* out = (float*)d_out;
    char* ws = (char*)d_ws;
    int*   cnt     = (int*)(ws + WS_CNT);
    int*   off     = (int*)(ws + WS_OFF);
    int*   list    = (int*)(ws + WS_LIST);
    float* w_entry = (float*)(ws + WS_W);
    unsigned short* g  = (unsigned short*)(ws + WS_G);
    unsigned short* Ax = (unsigned short*)(ws + WS_AX);
    unsigned short* y  = (unsigned short*)(ws + WS_Y);

    hipMemsetAsync(cnt, 0, E_NUM * sizeof(int), stream);
    router_kernel<<<N_TOK/4, 256, 0, stream>>>(x, rw, cnt, list, w_entry);
    prefix_kernel<<<1, 64, 0, stream>>>(cnt, off);
    gather_kernel<<<E_NUM*512, 256, 0, stream>>>(x, cnt, off, list, Ax);
    moe_gemm_kernel<1><<<32*32*E_NUM, 256, 0, stream>>>(Ax, W1, cnt, off, list, w_entry, g);
    moe_gemm_kernel<0><<<32*16*E_NUM, 256, 0, stream>>>(g,  W2, cnt, off, list, w_entry, y);
    combine_kernel<<<(out_size/8 + 255)/256, 256, 0, stream>>>(y, out);
}